// Round 18
// baseline (456.452 us; speedup 1.0000x reference)
//
#include <hip/hip_runtime.h>
#include <hip/hip_bf16.h>
#include <math.h>

typedef __attribute__((ext_vector_type(8))) __bf16 bf16x8;
typedef __attribute__((ext_vector_type(4))) float floatx4;
typedef __attribute__((ext_vector_type(8))) unsigned short ushort8v;

__device__ inline unsigned short f2u(float f) {
  __hip_bfloat16 h = __float2bfloat16(f);
  unsigned short u;
  __builtin_memcpy(&u, &h, 2);
  return u;
}

__device__ inline floatx4 mfma16(bf16x8 a, bf16x8 b, floatx4 c) {
  return __builtin_amdgcn_mfma_f32_16x16x32_bf16(a, b, c, 0, 0, 0);
}

__device__ inline void gload_lds16(const unsigned short* g, unsigned short* l) {
  __builtin_amdgcn_global_load_lds(
      (__attribute__((address_space(1))) void*)g,
      (__attribute__((address_space(3))) void*)l,
      16, 0, 0);
}

// ---------------- fused cast: x + 4 weights, one launch ----------------
__global__ __launch_bounds__(256) void castall(const float* __restrict__ x,
                                               const float* __restrict__ wq,
                                               const float* __restrict__ wk,
                                               const float* __restrict__ wv,
                                               const float* __restrict__ wo,
                                               unsigned short* __restrict__ x16,
                                               unsigned short* __restrict__ oq,
                                               unsigned short* __restrict__ ok,
                                               unsigned short* __restrict__ ov,
                                               unsigned short* __restrict__ oo,
                                               float qscale) {
  const int bid = blockIdx.x;
  const float* in;
  unsigned short* out;
  float s = 1.0f;
  int i;
  if (bid < 16384) {
    in = x; out = x16;
    i = bid * 256 + threadIdx.x;
  } else {
    const int tensor = (bid - 16384) >> 12;
    in = tensor == 0 ? wq : tensor == 1 ? wk : tensor == 2 ? wv : wo;
    out = tensor == 0 ? oq : tensor == 1 ? ok : tensor == 2 ? ov : oo;
    if (tensor == 0) s = qscale;
    i = ((bid - 16384) & 4095) * 256 + threadIdx.x;
  }
  const float4 v = reinterpret_cast<const float4*>(in)[i];
  ushort4 o;
  o.x = f2u(v.x * s);
  o.y = f2u(v.y * s);
  o.z = f2u(v.z * s);
  o.w = f2u(v.w * s);
  reinterpret_cast<ushort4*>(out)[i] = o;
}

// ---------------- 256x256 GEMM, 2-phase/K-tile (R16-verbatim) ----------
// OUT: 1 = f32 row-major + bias.
// OUT: 3 = fused QKV: n0<4096 -> bf16 row-major into Cb (stride 4096, Y2);
//          n0>=4096 -> kappa-Vtg via per-wave LDS transpose into (u16*)Cf.
//          kappa(tau) = 4*(tau&15) + (tau>>4) within each 64-block of t.
template <int OUT>
__global__ __launch_bounds__(512, 2)
void gemm256(const unsigned short* __restrict__ A,
             const unsigned short* __restrict__ B,
             unsigned short* __restrict__ Cb,
             float* __restrict__ Cf,
             const float* __restrict__ bias,
             int M, int N, int K) {
  extern __shared__ unsigned short lds[];
  const int t = threadIdx.x;
  const int w = t >> 6;
  const int l = t & 63;
  const int wm = w >> 2;
  const int wn = w & 3;
  const int fr = l & 15;
  const int fkb = l >> 4;
  const int key = fr & 7;
  const int sslot = (l & 7) ^ (l >> 3);

  const int m0 = blockIdx.y * 256;
  const int n0 = blockIdx.x * 256;
  const int T = K >> 6;

  auto stage = [&](const unsigned short* G, int rb, int kt2, int h, int ldsbase) {
    const int d2 = kt2 & 1;
    const int rt = h * 128 + w * 16 + (l >> 3);
    const unsigned short* s0 = G + (size_t)(rb + rt) * K + kt2 * 64 + sslot * 8;
    unsigned short* dst = lds + ldsbase + d2 * 16384 + h * 8192 + w * 1024;
    gload_lds16(s0, dst);
    gload_lds16(s0 + (size_t)8 * K, dst + 512);
  };

  floatx4 acc[8][4];
#pragma unroll
  for (int m = 0; m < 8; m++)
#pragma unroll
    for (int n = 0; n < 4; n++) acc[m][n] = (floatx4){0.f, 0.f, 0.f, 0.f};

  stage(A, m0, 0, 0, 0);
  stage(A, m0, 0, 1, 0);
  stage(B, n0, 0, 0, 32768);
  stage(B, n0, 0, 1, 32768);
  if (1 < T) {
    stage(B, n0, 1, 0, 32768);
    stage(B, n0, 1, 1, 32768);
    asm volatile("s_waitcnt vmcnt(4)" ::: "memory");
  } else {
    asm volatile("s_waitcnt vmcnt(0)" ::: "memory");
  }
  __builtin_amdgcn_s_barrier();

  for (int kt = 0; kt < T; ++kt) {
    const int d = kt & 1;
    const unsigned short* Ab = lds + d * 16384;
    const unsigned short* Bb = lds + 32768 + d * 16384;

    bf16x8 bfr[2][4];
#pragma unroll
    for (int kk = 0; kk < 2; kk++)
#pragma unroll
      for (int n = 0; n < 4; n++)
        bfr[kk][n] = *reinterpret_cast<const bf16x8*>(
            Bb + (wn * 64 + n * 16 + fr) * 64 + (((kk * 4 + fkb) ^ key)) * 8);

    bf16x8 af[4][2];

    // ---- phase A: m rows 0..3; stage A(kt+1) ----
#pragma unroll
    for (int m = 0; m < 4; m++) {
      af[m][0] = *reinterpret_cast<const bf16x8*>(
          Ab + (wm * 128 + m * 16 + fr) * 64 + ((fkb ^ key)) * 8);
      af[m][1] = *reinterpret_cast<const bf16x8*>(
          Ab + (wm * 128 + m * 16 + fr) * 64 + (((4 + fkb) ^ key)) * 8);
    }
    if (kt + 1 < T) {
      stage(A, m0, kt + 1, 0, 0);
      stage(A, m0, kt + 1, 1, 0);
    }
    __builtin_amdgcn_s_barrier();
    asm volatile("s_waitcnt lgkmcnt(0)");
    __builtin_amdgcn_s_setprio(1);
#pragma unroll
    for (int m = 0; m < 4; m++)
#pragma unroll
      for (int n = 0; n < 4; n++) {
        acc[m][n] = mfma16(af[m][0], bfr[0][n], acc[m][n]);
        acc[m][n] = mfma16(af[m][1], bfr[1][n], acc[m][n]);
      }
    __builtin_amdgcn_s_setprio(0);
    __builtin_amdgcn_s_barrier();

    // ---- phase B: m rows 4..7; stage B(kt+2); counted vmcnt ----
#pragma unroll
    for (int m = 0; m < 4; m++) {
      af[m][0] = *reinterpret_cast<const bf16x8*>(
          Ab + (wm * 128 + (m + 4) * 16 + fr) * 64 + ((fkb ^ key)) * 8);
      af[m][1] = *reinterpret_cast<const bf16x8*>(
          Ab + (wm * 128 + (m + 4) * 16 + fr) * 64 + (((4 + fkb) ^ key)) * 8);
    }
    if (kt + 2 < T) {
      stage(B, n0, kt + 2, 0, 32768);
      stage(B, n0, kt + 2, 1, 32768);
      asm volatile("s_waitcnt vmcnt(4)" ::: "memory");
    } else {
      asm volatile("s_waitcnt vmcnt(0)" ::: "memory");
    }
    __builtin_amdgcn_s_barrier();
    asm volatile("s_waitcnt lgkmcnt(0)");
    __builtin_amdgcn_s_setprio(1);
#pragma unroll
    for (int m = 0; m < 4; m++)
#pragma unroll
      for (int n = 0; n < 4; n++) {
        acc[m + 4][n] = mfma16(af[m][0], bfr[0][n], acc[m + 4][n]);
        acc[m + 4][n] = mfma16(af[m][1], bfr[1][n], acc[m + 4][n]);
      }
    __builtin_amdgcn_s_setprio(0);
    __builtin_amdgcn_s_barrier();
  }

  if (OUT == 3 && n0 >= 4096) {
    // kappa-Vtg write via per-wave LDS transpose (R13-verified epilogue).
    unsigned short* Vout = reinterpret_cast<unsigned short*>(Cf);
    unsigned short* TB = lds + w * (64 * 68);  // pad 68: conflict-free gather
    const int ec = l & 15;
    const int vbase = n0 + wn * 64 - 4096;
    const int hv = vbase >> 7;
    const int off64 = vbase & 127;  // 0 or 64
    const int bb = (m0 + wm * 128) >> 11;
    const int s = l & 7;
    const int dgrp = l >> 3;
#pragma unroll
    for (int h2 = 0; h2 < 2; h2++) {
#pragma unroll
      for (int mm = 0; mm < 4; mm++) {
#pragma unroll
        for (int n = 0; n < 4; n++) {
#pragma unroll
          for (int r = 0; r < 4; r++) {
            const int tau = mm * 16 + (l >> 4) * 4 + r;
            TB[tau * 68 + n * 16 + ec] = f2u(acc[h2 * 4 + mm][n][r]);
          }
        }
      }
      const int tbase = ((m0 + wm * 128) & 2047) + h2 * 64;
#pragma unroll
      for (int u8 = 0; u8 < 8; u8++) {
        const int dh = dgrp + 8 * u8;
        ushort8v buf;
#pragma unroll
        for (int e = 0; e < 8; e++) {
          const int tau = 16 * (e & 3) + 2 * s + (e >> 2);
          buf[e] = TB[tau * 68 + dh];
        }
        unsigned short* vp = Vout +
            (((size_t)(bb * 16 + hv)) * 128 + off64 + dh) * 2048 + tbase + 8 * s;
        *reinterpret_cast<ushort8v*>(vp) = buf;
      }
    }
  } else {
    const int er = (l >> 4) * 4;
    const int ec = l & 15;
#pragma unroll
    for (int m = 0; m < 8; m++) {
#pragma unroll
      for (int n = 0; n < 4; n++) {
        const int col = n0 + wn * 64 + n * 16 + ec;
#pragma unroll
        for (int r = 0; r < 4; r++) {
          const int row = m0 + wm * 128 + m * 16 + er + r;
          if (OUT == 1) {
            Cf[(size_t)row * N + col] = acc[m][n][r] + bias[col];
          } else {  // OUT==3, Q|K half: row-major bf16 into Y2 (stride 4096)
            Cb[(size_t)row * 4096 + col] = f2u(acc[m][n][r]);
          }
        }
      }
    }
  }
}

// ---------------- flash attention (R13 + extended V-swizzle involution) ----
// Y2: (8192 x 4096) bf16, cols [0,2048)=Q (pre-scaled by log2e/sqrt(Dh)),
// [2048,4096)=K.  Vtg: [64 bh][128 dh][2048 t-kappa-permuted] bf16.
// V LDS involution extended to kappaV(r) = (r&7) ^ (((r>>3)&1)<<2): rows fr
// and fr+8 now use disjoint slot-halves -> V b128 reads drop from 8-way to
// 4-way bank aliasing (Vt rows are 128B = 0 mod 32 banks, so only the slot
// XOR spreads banks). Applied to BOTH staging source and read offsets.
__global__ __launch_bounds__(256, 2)
void attn_kernel(const unsigned short* __restrict__ Y2,
                 const unsigned short* __restrict__ Vtg,
                 unsigned short* __restrict__ att) {
  __shared__ unsigned short Kt[64 * 128];   // 16 KB, [kvrow][slot16 swz]
  __shared__ unsigned short Vt[128 * 64];   // 16 KB, [dh][slot8 swz]
  __shared__ unsigned short Pl[4][32 * 72]; // 18 KB, per-wave P, stride 72

  const int t = threadIdx.x;
  const int w = t >> 6;
  const int l = t & 63;
  const int bid = blockIdx.x;
  const int bh = bid & 63;
  const int qt = bid >> 6;  // 0..15, 128 q-rows each
  const int b = bh >> 4;
  const int h = bh & 15;

  const size_t ybase = (size_t)b * 2048 * 4096 + (size_t)h * 128;
  const unsigned short* Qp = Y2 + ybase;
  const unsigned short* Kp = Y2 + ybase + 2048;
  const unsigned short* Vp = Vtg + (size_t)bh * 128 * 2048;

  const int fr = l & 15;
  const int fkb = l >> 4;
  const int key = fr & 7;
  const int keyv = (fr & 7) ^ (((fr >> 3) & 1) << 2);  // extended V involution

  const int ksr = t >> 4;
  const int ksl = (t & 15) ^ (ksr & 7);
  const unsigned short* Ksrc = Kp + (size_t)ksr * 4096 + ksl * 8;

  const int vsr = t >> 3;
  const int vsl = (t & 7) ^ (vsr & 7) ^ (((vsr >> 3) & 1) << 2);
  const unsigned short* Vsrc = Vp + (size_t)vsr * 2048 + vsl * 8;

  bf16x8 qf[2][4];
#pragma unroll
  for (int i = 0; i < 2; i++)
#pragma unroll
    for (int kk = 0; kk < 4; kk++)
      qf[i][kk] = *reinterpret_cast<const bf16x8*>(
          &Qp[(size_t)(qt * 128 + w * 32 + i * 16 + fr) * 4096 + kk * 32 + fkb * 8]);

  floatx4 oacc[2][8];
#pragma unroll
  for (int i = 0; i < 2; i++)
#pragma unroll
    for (int nt = 0; nt < 8; nt++) oacc[i][nt] = (floatx4){0.f, 0.f, 0.f, 0.f};
  float mrun[2][4], lsum[2][4];
#pragma unroll
  for (int i = 0; i < 2; i++)
#pragma unroll
    for (int r = 0; r < 4; r++) {
      mrun[i][r] = -INFINITY;
      lsum[i][r] = 0.f;
    }

  unsigned short* Pw = &Pl[w][0];

  // prologue: stage K(0), V(0)
#pragma unroll
  for (int c = 0; c < 4; c++)
    gload_lds16(Ksrc + (size_t)c * 16 * 4096, &Kt[c * 2048 + w * 512]);
#pragma unroll
  for (int c = 0; c < 4; c++)
    gload_lds16(Vsrc + (size_t)c * 32 * 2048, &Vt[c * 2048 + w * 512]);
  __syncthreads();  // vmcnt drained: K(0), V(0) ready

  for (int kv = 0; kv < 2048; kv += 64) {
    // ---- QK^T: 32 q-rows x 64 kv from Kt (log2-domain scores) ----
    floatx4 sacc[2][4];
#pragma unroll
    for (int i = 0; i < 2; i++)
#pragma unroll
      for (int nt = 0; nt < 4; nt++) sacc[i][nt] = (floatx4){0.f, 0.f, 0.f, 0.f};
#pragma unroll
    for (int nt = 0; nt < 4; nt++) {
#pragma unroll
      for (int kk = 0; kk < 4; kk++) {
        bf16x8 kf = *reinterpret_cast<const bf16x8*>(
            &Kt[((nt * 16 + fr) * 16 + ((kk * 4 + fkb) ^ key)) * 8]);
        sacc[0][nt] = mfma16(qf[0][kk], kf, sacc[0][nt]);
        sacc[1][nt] = mfma16(qf[1][kk], kf, sacc[1][nt]);
      }
    }

    // ---- softmax: shuffle-free common path (defer-max THR=11.5 log2) ----
    float mx4[2][4];
    float dmax = -INFINITY;
#pragma unroll
    for (int i = 0; i < 2; i++)
#pragma unroll
      for (int r = 0; r < 4; r++) {
        mx4[i][r] = fmaxf(fmaxf(sacc[i][0][r], sacc[i][1][r]),
                          fmaxf(sacc[i][2][r], sacc[i][3][r]));
        dmax = fmaxf(dmax, mx4[i][r] - mrun[i][r]);
      }
    if (__any(dmax > 11.5f)) {  // rare: full reduce + rescale
#pragma unroll
      for (int i = 0; i < 2; i++)
#pragma unroll
        for (int r = 0; r < 4; r++) {
          float mx = mx4[i][r];
          mx = fmaxf(mx, __shfl_xor(mx, 1));
          mx = fmaxf(mx, __shfl_xor(mx, 2));
          mx = fmaxf(mx, __shfl_xor(mx, 4));
          mx = fmaxf(mx, __shfl_xor(mx, 8));
          const float mn = fmaxf(mrun[i][r], mx);
          const float alpha = exp2f(mrun[i][r] - mn);
          mrun[i][r] = mn;
          lsum[i][r] *= alpha;
#pragma unroll
          for (int nt = 0; nt < 8; nt++) oacc[i][nt][r] *= alpha;
        }
    }
#pragma unroll
    for (int i = 0; i < 2; i++)
#pragma unroll
      for (int r = 0; r < 4; r++) {
        const float m = mrun[i][r];
        const float p0 = exp2f(sacc[i][0][r] - m);
        const float p1 = exp2f(sacc[i][1][r] - m);
        const float p2 = exp2f(sacc[i][2][r] - m);
        const float p3 = exp2f(sacc[i][3][r] - m);
        lsum[i][r] += (p0 + p1) + (p2 + p3);
        const int pr = i * 16 + fkb * 4 + r;
        // kappa-packed: logical kv {fr,16+fr,32+fr,48+fr} -> cols 4fr..4fr+3
        ushort4 pk;
        pk.x = f2u(p0);
        pk.y = f2u(p1);
        pk.z = f2u(p2);
        pk.w = f2u(p3);
        *reinterpret_cast<ushort4*>(&Pw[pr * 72 + 4 * fr]) = pk;
      }

    __syncthreads();  // bar1: all Kt reads done; prior V-stage drained

    // ---- stage K(kv+64); latency hides under PV ----
    if (kv + 64 < 2048) {
#pragma unroll
      for (int c = 0; c < 4; c++)
        gload_lds16(Ksrc + (size_t)(kv + 64 + c * 16) * 4096,
                    &Kt[c * 2048 + w * 512]);
    }

    // ---- PV: out(32x128) += P(32x64) @ V(64x128), kappa-consistent K-dim ----
    bf16x8 pf[2][2];
#pragma unroll
    for (int i = 0; i < 2; i++) {
      pf[i][0] = *reinterpret_cast<const bf16x8*>(&Pw[(i * 16 + fr) * 72 + fkb * 8]);
      pf[i][1] = *reinterpret_cast<const bf16x8*>(&Pw[(i * 16 + fr) * 72 + 32 + fkb * 8]);
    }
#pragma unroll
    for (int nt = 0; nt < 8; nt++) {
      const unsigned short* vr = &Vt[(nt * 16 + fr) * 64];
      bf16x8 vf0 = *reinterpret_cast<const bf16x8*>(vr + (fkb ^ keyv) * 8);
      bf16x8 vf1 = *reinterpret_cast<const bf16x8*>(vr + (((fkb + 4) ^ keyv)) * 8);
#pragma unroll
      for (int i = 0; i < 2; i++) {
        oacc[i][nt] = mfma16(pf[i][0], vf0, oacc[i][nt]);
        oacc[i][nt] = mfma16(pf[i][1], vf1, oacc[i][nt]);
      }
    }

    __syncthreads();  // bar2: all Vt reads done; K(kv+64) drained

    // ---- stage V(kv+64); latency hides under next QK^T+softmax ----
    if (kv + 64 < 2048) {
#pragma unroll
      for (int c = 0; c < 4; c++)
        gload_lds16(Vsrc + (size_t)c * 32 * 2048 + (kv + 64),
                    &Vt[c * 2048 + w * 512]);
    }
  }

  // ---- epilogue: reduce per-lane lsum partials once, then write ----
#pragma unroll
  for (int i = 0; i < 2; i++) {
#pragma unroll
    for (int r = 0; r < 4; r++) {
      float s = lsum[i][r];
      s += __shfl_xor(s, 1);
      s += __shfl_xor(s, 2);
      s += __shfl_xor(s, 4);
      s += __shfl_xor(s, 8);
      const float inv = 1.0f / s;
      const int row = qt * 128 + w * 32 + i * 16 + fkb * 4 + r;
      unsigned short* op = att + ((size_t)b * 2048 + row) * 2048 + h * 128 + fr;
#pragma unroll
      for (int nt = 0; nt < 8; nt++) op[nt * 16] = f2u(oacc[i][nt][r] * inv);
    }
  }
}

// ---------------- launch ----------------
extern "C" void kernel_launch(void* const* d_in, const int* in_sizes, int n_in,
                              void* d_out, int out_size, void* d_ws, size_t ws_size,
                              hipStream_t stream) {
  const float* x = (const float*)d_in[0];
  const float* wq = (const float*)d_in[1];
  const float* wk = (const float*)d_in[2];
  const float* wv = (const float*)d_in[3];
  const float* wo = (const float*)d_in[4];
  const float* bo = (const float*)d_in[5];

  unsigned short* ws = (unsigned short*)d_ws;
  unsigned short* x16 = ws;                      // 16,777,216
  unsigned short* wqkv16 = x16 + 16777216;       // 12,582,912
  unsigned short* wo16 = wqkv16 + 12582912;      // 4,194,304
  unsigned short* Y2 = wo16 + 4194304;           // 33,554,432 (8192 x 4096, Q|K)
  unsigned short* Vtg = Y2 + 33554432;           // 16,777,216 (64 x 128 x 2048)
  unsigned short* att16 = Vtg + 16777216;        // 16,777,216
  // total 100,663,296 ushorts = 201.3 MB

  // log2(e)/sqrt(128): scores land in log2 domain -> exp2f softmax
  const float sscale = 0.12751744900765256f;

  hipFuncSetAttribute(reinterpret_cast<const void*>(gemm256<1>),
                      hipFuncAttributeMaxDynamicSharedMemorySize, 131072);
  hipFuncSetAttribute(reinterpret_cast<const void*>(gemm256<3>),
                      hipFuncAttributeMaxDynamicSharedMemorySize, 131072);

  castall<<<32768, 256, 0, stream>>>(x, wq, wk, wv, wo,
                                     x16, wqkv16, wqkv16 + 4194304,
                                     wqkv16 + 8388608, wo16, sscale);

  // fused QKV projection: N=6144 over [wq;wk;wv]; cols<4096 -> Y2,
  // cols>=4096 -> Vtg (kappa-transposed). 2D grid (no XCD swizzle).
  dim3 gqkv(24, 32);
  gemm256<3><<<gqkv, 512, 131072, stream>>>(x16, wqkv16, Y2, (float*)Vtg,
                                            nullptr, 8192, 6144, 2048);

  attn_kernel<<<1024, 256, 0, stream>>>(Y2, Vtg, att16);

  dim3 go(8, 32);
  gemm256<1><<<go, 512, 131072, stream>>>(att16, wo16, nullptr, (float*)d_out,
                                          bo, 8192, 2048, 2048);
}

// Round 19
// 451.356 us; speedup vs baseline: 1.0113x; 1.0113x over previous
//
#include <hip/hip_runtime.h>
#include <hip/hip_bf16.h>
#include <math.h>

typedef __attribute__((ext_vector_type(8))) __bf16 bf16x8;
typedef __attribute__((ext_vector_type(4))) float floatx4;
typedef __attribute__((ext_vector_type(8))) unsigned short ushort8v;

__device__ inline unsigned short f2u(float f) {
  __hip_bfloat16 h = __float2bfloat16(f);
  unsigned short u;
  __builtin_memcpy(&u, &h, 2);
  return u;
}

__device__ inline floatx4 mfma16(bf16x8 a, bf16x8 b, floatx4 c) {
  return __builtin_amdgcn_mfma_f32_16x16x32_bf16(a, b, c, 0, 0, 0);
}

__device__ inline void gload_lds16(const unsigned short* g, unsigned short* l) {
  __builtin_amdgcn_global_load_lds(
      (__attribute__((address_space(1))) void*)g,
      (__attribute__((address_space(3))) void*)l,
      16, 0, 0);
}

// ---------------- fused cast: x + 4 weights, one launch ----------------
__global__ __launch_bounds__(256) void castall(const float* __restrict__ x,
                                               const float* __restrict__ wq,
                                               const float* __restrict__ wk,
                                               const float* __restrict__ wv,
                                               const float* __restrict__ wo,
                                               unsigned short* __restrict__ x16,
                                               unsigned short* __restrict__ oq,
                                               unsigned short* __restrict__ ok,
                                               unsigned short* __restrict__ ov,
                                               unsigned short* __restrict__ oo,
                                               float qscale) {
  const int bid = blockIdx.x;
  const float* in;
  unsigned short* out;
  float s = 1.0f;
  int i;
  if (bid < 16384) {
    in = x; out = x16;
    i = bid * 256 + threadIdx.x;
  } else {
    const int tensor = (bid - 16384) >> 12;
    in = tensor == 0 ? wq : tensor == 1 ? wk : tensor == 2 ? wv : wo;
    out = tensor == 0 ? oq : tensor == 1 ? ok : tensor == 2 ? ov : oo;
    if (tensor == 0) s = qscale;
    i = ((bid - 16384) & 4095) * 256 + threadIdx.x;
  }
  const float4 v = reinterpret_cast<const float4*>(in)[i];
  ushort4 o;
  o.x = f2u(v.x * s);
  o.y = f2u(v.y * s);
  o.z = f2u(v.z * s);
  o.w = f2u(v.w * s);
  reinterpret_cast<ushort4*>(out)[i] = o;
}

// ---------------- 256x256 GEMM, 2-phase/K-tile (R16-verbatim) ----------
// OUT: 1 = f32 row-major + bias.
// OUT: 3 = fused QKV: n0<4096 -> bf16 row-major into Cb (stride 4096, Y2);
//          n0>=4096 -> kappa-Vtg via per-wave LDS transpose into (u16*)Cf.
//          kappa(tau) = 4*(tau&15) + (tau>>4) within each 64-block of t.
template <int OUT>
__global__ __launch_bounds__(512, 2)
void gemm256(const unsigned short* __restrict__ A,
             const unsigned short* __restrict__ B,
             unsigned short* __restrict__ Cb,
             float* __restrict__ Cf,
             const float* __restrict__ bias,
             int M, int N, int K) {
  extern __shared__ unsigned short lds[];
  const int t = threadIdx.x;
  const int w = t >> 6;
  const int l = t & 63;
  const int wm = w >> 2;
  const int wn = w & 3;
  const int fr = l & 15;
  const int fkb = l >> 4;
  const int key = fr & 7;
  const int sslot = (l & 7) ^ (l >> 3);

  const int m0 = blockIdx.y * 256;
  const int n0 = blockIdx.x * 256;
  const int T = K >> 6;

  auto stage = [&](const unsigned short* G, int rb, int kt2, int h, int ldsbase) {
    const int d2 = kt2 & 1;
    const int rt = h * 128 + w * 16 + (l >> 3);
    const unsigned short* s0 = G + (size_t)(rb + rt) * K + kt2 * 64 + sslot * 8;
    unsigned short* dst = lds + ldsbase + d2 * 16384 + h * 8192 + w * 1024;
    gload_lds16(s0, dst);
    gload_lds16(s0 + (size_t)8 * K, dst + 512);
  };

  floatx4 acc[8][4];
#pragma unroll
  for (int m = 0; m < 8; m++)
#pragma unroll
    for (int n = 0; n < 4; n++) acc[m][n] = (floatx4){0.f, 0.f, 0.f, 0.f};

  stage(A, m0, 0, 0, 0);
  stage(A, m0, 0, 1, 0);
  stage(B, n0, 0, 0, 32768);
  stage(B, n0, 0, 1, 32768);
  if (1 < T) {
    stage(B, n0, 1, 0, 32768);
    stage(B, n0, 1, 1, 32768);
    asm volatile("s_waitcnt vmcnt(4)" ::: "memory");
  } else {
    asm volatile("s_waitcnt vmcnt(0)" ::: "memory");
  }
  __builtin_amdgcn_s_barrier();

  for (int kt = 0; kt < T; ++kt) {
    const int d = kt & 1;
    const unsigned short* Ab = lds + d * 16384;
    const unsigned short* Bb = lds + 32768 + d * 16384;

    bf16x8 bfr[2][4];
#pragma unroll
    for (int kk = 0; kk < 2; kk++)
#pragma unroll
      for (int n = 0; n < 4; n++)
        bfr[kk][n] = *reinterpret_cast<const bf16x8*>(
            Bb + (wn * 64 + n * 16 + fr) * 64 + (((kk * 4 + fkb) ^ key)) * 8);

    bf16x8 af[4][2];

    // ---- phase A: m rows 0..3; stage A(kt+1) ----
#pragma unroll
    for (int m = 0; m < 4; m++) {
      af[m][0] = *reinterpret_cast<const bf16x8*>(
          Ab + (wm * 128 + m * 16 + fr) * 64 + ((fkb ^ key)) * 8);
      af[m][1] = *reinterpret_cast<const bf16x8*>(
          Ab + (wm * 128 + m * 16 + fr) * 64 + (((4 + fkb) ^ key)) * 8);
    }
    if (kt + 1 < T) {
      stage(A, m0, kt + 1, 0, 0);
      stage(A, m0, kt + 1, 1, 0);
    }
    __builtin_amdgcn_s_barrier();
    asm volatile("s_waitcnt lgkmcnt(0)");
    __builtin_amdgcn_s_setprio(1);
#pragma unroll
    for (int m = 0; m < 4; m++)
#pragma unroll
      for (int n = 0; n < 4; n++) {
        acc[m][n] = mfma16(af[m][0], bfr[0][n], acc[m][n]);
        acc[m][n] = mfma16(af[m][1], bfr[1][n], acc[m][n]);
      }
    __builtin_amdgcn_s_setprio(0);
    __builtin_amdgcn_s_barrier();

    // ---- phase B: m rows 4..7; stage B(kt+2); counted vmcnt ----
#pragma unroll
    for (int m = 0; m < 4; m++) {
      af[m][0] = *reinterpret_cast<const bf16x8*>(
          Ab + (wm * 128 + (m + 4) * 16 + fr) * 64 + ((fkb ^ key)) * 8);
      af[m][1] = *reinterpret_cast<const bf16x8*>(
          Ab + (wm * 128 + (m + 4) * 16 + fr) * 64 + (((4 + fkb) ^ key)) * 8);
    }
    if (kt + 2 < T) {
      stage(B, n0, kt + 2, 0, 32768);
      stage(B, n0, kt + 2, 1, 32768);
      asm volatile("s_waitcnt vmcnt(4)" ::: "memory");
    } else {
      asm volatile("s_waitcnt vmcnt(0)" ::: "memory");
    }
    __builtin_amdgcn_s_barrier();
    asm volatile("s_waitcnt lgkmcnt(0)");
    __builtin_amdgcn_s_setprio(1);
#pragma unroll
    for (int m = 0; m < 4; m++)
#pragma unroll
      for (int n = 0; n < 4; n++) {
        acc[m + 4][n] = mfma16(af[m][0], bfr[0][n], acc[m + 4][n]);
        acc[m + 4][n] = mfma16(af[m][1], bfr[1][n], acc[m + 4][n]);
      }
    __builtin_amdgcn_s_setprio(0);
    __builtin_amdgcn_s_barrier();
  }

  if (OUT == 3 && n0 >= 4096) {
    // kappa-Vtg write via per-wave LDS transpose (R13-verified epilogue).
    unsigned short* Vout = reinterpret_cast<unsigned short*>(Cf);
    unsigned short* TB = lds + w * (64 * 68);  // pad 68: conflict-free gather
    const int ec = l & 15;
    const int vbase = n0 + wn * 64 - 4096;
    const int hv = vbase >> 7;
    const int off64 = vbase & 127;  // 0 or 64
    const int bb = (m0 + wm * 128) >> 11;
    const int s = l & 7;
    const int dgrp = l >> 3;
#pragma unroll
    for (int h2 = 0; h2 < 2; h2++) {
#pragma unroll
      for (int mm = 0; mm < 4; mm++) {
#pragma unroll
        for (int n = 0; n < 4; n++) {
#pragma unroll
          for (int r = 0; r < 4; r++) {
            const int tau = mm * 16 + (l >> 4) * 4 + r;
            TB[tau * 68 + n * 16 + ec] = f2u(acc[h2 * 4 + mm][n][r]);
          }
        }
      }
      const int tbase = ((m0 + wm * 128) & 2047) + h2 * 64;
#pragma unroll
      for (int u8 = 0; u8 < 8; u8++) {
        const int dh = dgrp + 8 * u8;
        ushort8v buf;
#pragma unroll
        for (int e = 0; e < 8; e++) {
          const int tau = 16 * (e & 3) + 2 * s + (e >> 2);
          buf[e] = TB[tau * 68 + dh];
        }
        unsigned short* vp = Vout +
            (((size_t)(bb * 16 + hv)) * 128 + off64 + dh) * 2048 + tbase + 8 * s;
        *reinterpret_cast<ushort8v*>(vp) = buf;
      }
    }
  } else {
    const int er = (l >> 4) * 4;
    const int ec = l & 15;
#pragma unroll
    for (int m = 0; m < 8; m++) {
#pragma unroll
      for (int n = 0; n < 4; n++) {
        const int col = n0 + wn * 64 + n * 16 + ec;
#pragma unroll
        for (int r = 0; r < 4; r++) {
          const int row = m0 + wm * 128 + m * 16 + er + r;
          if (OUT == 1) {
            Cf[(size_t)row * N + col] = acc[m][n][r] + bias[col];
          } else {  // OUT==3, Q|K half: row-major bf16 into Y2 (stride 4096)
            Cb[(size_t)row * 4096 + col] = f2u(acc[m][n][r]);
          }
        }
      }
    }
  }
}

// ---------------- flash attention (R13-verbatim: passing, ~206us) ----
// Y2: (8192 x 4096) bf16, cols [0,2048)=Q (pre-scaled by log2e/sqrt(Dh)),
// [2048,4096)=K.  Vtg: [64 bh][128 dh][2048 t-kappa-permuted] bf16.
// kappa (within each 64-block): tau stored at 4*(tau&15)+(tau>>4).
// P stored in the SAME kappa order -> one ds_write_b64 per lane-row.
__global__ __launch_bounds__(256, 2)
void attn_kernel(const unsigned short* __restrict__ Y2,
                 const unsigned short* __restrict__ Vtg,
                 unsigned short* __restrict__ att) {
  __shared__ unsigned short Kt[64 * 128];   // 16 KB, [kvrow][slot16 swz]
  __shared__ unsigned short Vt[128 * 64];   // 16 KB, [dh][slot8 swz]
  __shared__ unsigned short Pl[4][32 * 72]; // 18 KB, per-wave P, stride 72

  const int t = threadIdx.x;
  const int w = t >> 6;
  const int l = t & 63;
  const int bid = blockIdx.x;
  const int bh = bid & 63;
  const int qt = bid >> 6;  // 0..15, 128 q-rows each
  const int b = bh >> 4;
  const int h = bh & 15;

  const size_t ybase = (size_t)b * 2048 * 4096 + (size_t)h * 128;
  const unsigned short* Qp = Y2 + ybase;
  const unsigned short* Kp = Y2 + ybase + 2048;
  const unsigned short* Vp = Vtg + (size_t)bh * 128 * 2048;

  const int fr = l & 15;
  const int fkb = l >> 4;
  const int key = fr & 7;

  const int ksr = t >> 4;
  const int ksl = (t & 15) ^ (ksr & 7);
  const unsigned short* Ksrc = Kp + (size_t)ksr * 4096 + ksl * 8;

  const int vsr = t >> 3;
  const int vsl = (t & 7) ^ (vsr & 7);
  const unsigned short* Vsrc = Vp + (size_t)vsr * 2048 + vsl * 8;

  bf16x8 qf[2][4];
#pragma unroll
  for (int i = 0; i < 2; i++)
#pragma unroll
    for (int kk = 0; kk < 4; kk++)
      qf[i][kk] = *reinterpret_cast<const bf16x8*>(
          &Qp[(size_t)(qt * 128 + w * 32 + i * 16 + fr) * 4096 + kk * 32 + fkb * 8]);

  floatx4 oacc[2][8];
#pragma unroll
  for (int i = 0; i < 2; i++)
#pragma unroll
    for (int nt = 0; nt < 8; nt++) oacc[i][nt] = (floatx4){0.f, 0.f, 0.f, 0.f};
  float mrun[2][4], lsum[2][4];
#pragma unroll
  for (int i = 0; i < 2; i++)
#pragma unroll
    for (int r = 0; r < 4; r++) {
      mrun[i][r] = -INFINITY;
      lsum[i][r] = 0.f;
    }

  unsigned short* Pw = &Pl[w][0];

  // prologue: stage K(0), V(0)
#pragma unroll
  for (int c = 0; c < 4; c++)
    gload_lds16(Ksrc + (size_t)c * 16 * 4096, &Kt[c * 2048 + w * 512]);
#pragma unroll
  for (int c = 0; c < 4; c++)
    gload_lds16(Vsrc + (size_t)c * 32 * 2048, &Vt[c * 2048 + w * 512]);
  __syncthreads();  // vmcnt drained: K(0), V(0) ready

  for (int kv = 0; kv < 2048; kv += 64) {
    // ---- QK^T: 32 q-rows x 64 kv from Kt (log2-domain scores) ----
    floatx4 sacc[2][4];
#pragma unroll
    for (int i = 0; i < 2; i++)
#pragma unroll
      for (int nt = 0; nt < 4; nt++) sacc[i][nt] = (floatx4){0.f, 0.f, 0.f, 0.f};
#pragma unroll
    for (int nt = 0; nt < 4; nt++) {
#pragma unroll
      for (int kk = 0; kk < 4; kk++) {
        bf16x8 kf = *reinterpret_cast<const bf16x8*>(
            &Kt[((nt * 16 + fr) * 16 + ((kk * 4 + fkb) ^ key)) * 8]);
        sacc[0][nt] = mfma16(qf[0][kk], kf, sacc[0][nt]);
        sacc[1][nt] = mfma16(qf[1][kk], kf, sacc[1][nt]);
      }
    }

    // ---- softmax: shuffle-free common path (defer-max THR=11.5 log2) ----
    float mx4[2][4];
    float dmax = -INFINITY;
#pragma unroll
    for (int i = 0; i < 2; i++)
#pragma unroll
      for (int r = 0; r < 4; r++) {
        mx4[i][r] = fmaxf(fmaxf(sacc[i][0][r], sacc[i][1][r]),
                          fmaxf(sacc[i][2][r], sacc[i][3][r]));
        dmax = fmaxf(dmax, mx4[i][r] - mrun[i][r]);
      }
    if (__any(dmax > 11.5f)) {  // rare: full reduce + rescale
#pragma unroll
      for (int i = 0; i < 2; i++)
#pragma unroll
        for (int r = 0; r < 4; r++) {
          float mx = mx4[i][r];
          mx = fmaxf(mx, __shfl_xor(mx, 1));
          mx = fmaxf(mx, __shfl_xor(mx, 2));
          mx = fmaxf(mx, __shfl_xor(mx, 4));
          mx = fmaxf(mx, __shfl_xor(mx, 8));
          const float mn = fmaxf(mrun[i][r], mx);
          const float alpha = exp2f(mrun[i][r] - mn);
          mrun[i][r] = mn;
          lsum[i][r] *= alpha;
#pragma unroll
          for (int nt = 0; nt < 8; nt++) oacc[i][nt][r] *= alpha;
        }
    }
#pragma unroll
    for (int i = 0; i < 2; i++)
#pragma unroll
      for (int r = 0; r < 4; r++) {
        const float m = mrun[i][r];
        const float p0 = exp2f(sacc[i][0][r] - m);
        const float p1 = exp2f(sacc[i][1][r] - m);
        const float p2 = exp2f(sacc[i][2][r] - m);
        const float p3 = exp2f(sacc[i][3][r] - m);
        lsum[i][r] += (p0 + p1) + (p2 + p3);
        const int pr = i * 16 + fkb * 4 + r;
        // kappa-packed: logical kv {fr,16+fr,32+fr,48+fr} -> cols 4fr..4fr+3
        ushort4 pk;
        pk.x = f2u(p0);
        pk.y = f2u(p1);
        pk.z = f2u(p2);
        pk.w = f2u(p3);
        *reinterpret_cast<ushort4*>(&Pw[pr * 72 + 4 * fr]) = pk;
      }

    __syncthreads();  // bar1: all Kt reads done; prior V-stage drained

    // ---- stage K(kv+64); latency hides under PV ----
    if (kv + 64 < 2048) {
#pragma unroll
      for (int c = 0; c < 4; c++)
        gload_lds16(Ksrc + (size_t)(kv + 64 + c * 16) * 4096,
                    &Kt[c * 2048 + w * 512]);
    }

    // ---- PV: out(32x128) += P(32x64) @ V(64x128), kappa-consistent K-dim ----
    bf16x8 pf[2][2];
#pragma unroll
    for (int i = 0; i < 2; i++) {
      pf[i][0] = *reinterpret_cast<const bf16x8*>(&Pw[(i * 16 + fr) * 72 + fkb * 8]);
      pf[i][1] = *reinterpret_cast<const bf16x8*>(&Pw[(i * 16 + fr) * 72 + 32 + fkb * 8]);
    }
#pragma unroll
    for (int nt = 0; nt < 8; nt++) {
      const unsigned short* vr = &Vt[(nt * 16 + fr) * 64];
      bf16x8 vf0 = *reinterpret_cast<const bf16x8*>(vr + (fkb ^ key) * 8);
      bf16x8 vf1 = *reinterpret_cast<const bf16x8*>(vr + ((fkb + 4) ^ key) * 8);
#pragma unroll
      for (int i = 0; i < 2; i++) {
        oacc[i][nt] = mfma16(pf[i][0], vf0, oacc[i][nt]);
        oacc[i][nt] = mfma16(pf[i][1], vf1, oacc[i][nt]);
      }
    }

    __syncthreads();  // bar2: all Vt reads done; K(kv+64) drained

    // ---- stage V(kv+64); latency hides under next QK^T+softmax ----
    if (kv + 64 < 2048) {
#pragma unroll
      for (int c = 0; c < 4; c++)
        gload_lds16(Vsrc + (size_t)c * 32 * 2048 + (kv + 64),
                    &Vt[c * 2048 + w * 512]);
    }
  }

  // ---- epilogue: reduce per-lane lsum partials once, then write ----
#pragma unroll
  for (int i = 0; i < 2; i++) {
#pragma unroll
    for (int r = 0; r < 4; r++) {
      float s = lsum[i][r];
      s += __shfl_xor(s, 1);
      s += __shfl_xor(s, 2);
      s += __shfl_xor(s, 4);
      s += __shfl_xor(s, 8);
      const float inv = 1.0f / s;
      const int row = qt * 128 + w * 32 + i * 16 + fkb * 4 + r;
      unsigned short* op = att + ((size_t)b * 2048 + row) * 2048 + h * 128 + fr;
#pragma unroll
      for (int nt = 0; nt < 8; nt++) op[nt * 16] = f2u(oacc[i][nt][r] * inv);
    }
  }
}

// ---------------- launch ----------------
extern "C" void kernel_launch(void* const* d_in, const int* in_sizes, int n_in,
                              void* d_out, int out_size, void* d_ws, size_t ws_size,
                              hipStream_t stream) {
  const float* x = (const float*)d_in[0];
  const float* wq = (const float*)d_in[1];
  const float* wk = (const float*)d_in[2];
  const float* wv = (const float*)d_in[3];
  const float* wo = (const float*)d_in[4];
  const float* bo = (const float*)d_in[5];

  unsigned short* ws = (unsigned short*)d_ws;
  unsigned short* x16 = ws;                      // 16,777,216
  unsigned short* wqkv16 = x16 + 16777216;       // 12,582,912
  unsigned short* wo16 = wqkv16 + 12582912;      // 4,194,304
  unsigned short* Y2 = wo16 + 4194304;           // 33,554,432 (8192 x 4096, Q|K)
  unsigned short* Vtg = Y2 + 33554432;           // 16,777,216 (64 x 128 x 2048)
  unsigned short* att16 = Vtg + 16777216;        // 16,777,216
  // total 100,663,296 ushorts = 201.3 MB

  // log2(e)/sqrt(128): scores land in log2 domain -> exp2f softmax
  const float sscale = 0.12751744900765256f;

  hipFuncSetAttribute(reinterpret_cast<const void*>(gemm256<1>),
                      hipFuncAttributeMaxDynamicSharedMemorySize, 131072);
  hipFuncSetAttribute(reinterpret_cast<const void*>(gemm256<3>),
                      hipFuncAttributeMaxDynamicSharedMemorySize, 131072);

  castall<<<32768, 256, 0, stream>>>(x, wq, wk, wv, wo,
                                     x16, wqkv16, wqkv16 + 4194304,
                                     wqkv16 + 8388608, wo16, sscale);

  // fused QKV projection: N=6144 over [wq;wk;wv]; cols<4096 -> Y2,
  // cols>=4096 -> Vtg (kappa-transposed). 2D grid (no XCD swizzle).
  dim3 gqkv(24, 32);
  gemm256<3><<<gqkv, 512, 131072, stream>>>(x16, wqkv16, Y2, (float*)Vtg,
                                            nullptr, 8192, 6144, 2048);

  attn_kernel<<<1024, 256, 0, stream>>>(Y2, Vtg, att16);

  dim3 go(8, 32);
  gemm256<1><<<go, 512, 131072, stream>>>(att16, wo16, nullptr, (float*)d_out,
                                          bo, 8192, 2048, 2048);
}